// Round 9
// baseline (28.950 us; speedup 1.0000x reference)
//
#include <hip/hip_runtime.h>
#include <math.h>

// Problem constants
#define Dq 512
#define Vq 50257
#define Kq 100
#define KP 112              // K padded to 7*16
#define NORM_TERM 10.8249051f   // log(50257)
#define LOGK 4.6051702f         // log(100)
#define NBLK 1024           // 16384 positions / 16 per block
#define DT_STRIDE 3584      // KP*32 elements per d-chunk slab

typedef __attribute__((ext_vector_type(8))) short short8;
typedef __attribute__((ext_vector_type(4))) float floatx4;
typedef __attribute__((ext_vector_type(4))) unsigned short ushort4v;
typedef __attribute__((ext_vector_type(8))) unsigned short ushort8v;

__device__ __forceinline__ unsigned short f2bf(float f) {
    union { float f; unsigned u; } v; v.f = f;
    unsigned r = v.u + 0x7FFFu + ((v.u >> 16) & 1u);   // RNE
    return (unsigned short)(r >> 16);
}

__device__ __forceinline__ short8 cvt8(floatx4 a, floatx4 b) {
    short8 o;
    o[0] = (short)f2bf(a.x); o[1] = (short)f2bf(a.y);
    o[2] = (short)f2bf(a.z); o[3] = (short)f2bf(a.w);
    o[4] = (short)f2bf(b.x); o[5] = (short)f2bf(b.y);
    o[6] = (short)f2bf(b.z); o[7] = (short)f2bf(b.w);
    return o;
}

__device__ __forceinline__ float dot4(floatx4 a, floatx4 b) {
    return a.x*b.x + a.y*b.y + a.z*b.z + a.w*b.w;
}

__device__ __forceinline__ float log_sigmoid(float x) {
    return fminf(x, 0.f) - __logf(1.f + __expf(-fabsf(x)));
}

// Gather + convert noise rows to bf16, TRANSPOSED chunk-major layout:
// element (k, d) at nBT[(d>>5)*DT_STRIDE + k*32 + (d&31)]. A wave reading
// 16 k-rows x 4 chunks of one dt hits ONE contiguous 1KB block.
__global__ void prep_noise(const float* __restrict__ emb_w,
                           const float* __restrict__ emb_b,
                           const float* __restrict__ lpn,
                           const int* __restrict__ ns,
                           unsigned short* __restrict__ nBT,
                           float* __restrict__ nAdj) {
    int k = blockIdx.x;     // 0..111
    int t = threadIdx.x;    // 0..127; d = t*4 .. t*4+3
    size_t off = (size_t)(t >> 3) * DT_STRIDE + k * 32 + (t & 7) * 4;
    if (k < Kq) {
        int row = ns[k];
        floatx4 v = ((const floatx4*)(emb_w + (size_t)row * Dq))[t];
        ushort4v o;
        o.x = f2bf(v.x); o.y = f2bf(v.y); o.z = f2bf(v.z); o.w = f2bf(v.w);
        *(ushort4v*)(nBT + off) = o;
        if (t == 0) nAdj[k] = emb_b[row] - NORM_TERM - lpn[row] - LOGK;
    } else {
        ushort4v z; z.x = 0; z.y = 0; z.z = 0; z.w = 0;
        *(ushort4v*)(nBT + off) = z;
        if (t == 0) nAdj[k] = 0.f;
    }
}

// Block = 4 waves = 16 positions. Staging: per iteration a wave reads ONE
// full input row (2KB contiguous) + that position's target row (2KB
// contiguous), computes the fp32 target dot in VALU (shfl-reduced to
// tdot[row] in LDS), and writes the input row to LDS bf16 (XOR-swizzled).
// ONE barrier. Then noise MFMA from transposed nBT (contiguous 1KB/instr):
// w0:{0,1} w1:{2,3} w2:{4,5} w3:{6}+target epilogue from tdot.
__global__ __launch_bounds__(256, 4) void nce_main(
    const float* __restrict__ input,     // [16384][512]
    const float* __restrict__ emb_w,     // [V][512]
    const float* __restrict__ emb_b,     // [V]
    const float* __restrict__ lpn,       // [V]
    const int* __restrict__ target,      // [16384]
    const unsigned short* __restrict__ nBT,  // [16][112][32] bf16
    const float* __restrict__ nAdj,          // [112]
    float* __restrict__ partials)            // [4096]
{
    __shared__ unsigned short A_lds[16 * 512];  // byte: row*1024 + (2c ^ ((row&7)<<4))
    __shared__ float tdot[16];

    int tid  = threadIdx.x;
    int lane = tid & 63;
    int w    = tid >> 6;            // 0..3
    int pos0 = (int)blockIdx.x * 16;
    int r16  = lane & 15;
    int g4   = lane >> 4;

    // ---- Stage: 4 rows per wave; full-row 2KB bursts for input & target ----
#pragma unroll
    for (int j = 0; j < 4; ++j) {
        int row = w * 4 + j;                         // 0..15
        const float* src = input + (size_t)(pos0 + row) * Dq + lane * 8;
        int tg = target[pos0 + row];                 // wave-uniform -> scalar
        const float* tsrc = emb_w + (size_t)tg * Dq + lane * 8;
        floatx4 x0 = *(const floatx4*)(src);
        floatx4 x1 = *(const floatx4*)(src + 4);
        floatx4 t0 = *(const floatx4*)(tsrc);
        floatx4 t1 = *(const floatx4*)(tsrc + 4);
        float s = dot4(x0, t0) + dot4(x1, t1);
#pragma unroll
        for (int off = 32; off >= 1; off >>= 1)
            s += __shfl_xor(s, off);
        if (lane == 0) tdot[row] = s;
        char* base = (char*)A_lds + row * 1024;
        *(ushort8v*)(base + ((lane * 16) ^ ((row & 7) << 4))) = (ushort8v)cvt8(x0, x1);
    }
    __syncthreads();

    const char* abase = (const char*)A_lds + r16 * 1024;
    int asw = (r16 & 7) << 4;

    float contrib = 0.f;

    if (w < 3) {
        // ---- Noise k-tiles 2w, 2w+1: per dt, two contiguous 1KB bursts ----
        const unsigned short* p0 = nBT + (size_t)(2 * w) * 512 + r16 * 32 + g4 * 8;
        floatx4 acc0 = {0.f, 0.f, 0.f, 0.f};
        floatx4 acc1 = {0.f, 0.f, 0.f, 0.f};
#pragma unroll
        for (int dt = 0; dt < 16; ++dt) {
            short8 a  = *(const short8*)(abase + ((dt * 64 + g4 * 16) ^ asw));
            short8 f0 = *(const short8*)(p0 + (size_t)dt * DT_STRIDE);
            short8 f1 = *(const short8*)(p0 + (size_t)dt * DT_STRIDE + 512);
            acc0 = __builtin_amdgcn_mfma_f32_16x16x32_bf16(a, f0, acc0, 0, 0, 0);
            acc1 = __builtin_amdgcn_mfma_f32_16x16x32_bf16(a, f1, acc1, 0, 0, 0);
        }
        float adj0 = nAdj[w * 32 + r16];
        float adj1 = nAdj[w * 32 + 16 + r16];
#pragma unroll
        for (int r = 0; r < 4; ++r) {
            contrib += log_sigmoid(-(acc0[r] + adj0));
            contrib += log_sigmoid(-(acc1[r] + adj1));
        }
    } else {
        // ---- Noise k-tile 6 (k=96..111, valid <100) ----
        const unsigned short* p6 = nBT + (size_t)6 * 512 + r16 * 32 + g4 * 8;
        floatx4 acc6 = {0.f, 0.f, 0.f, 0.f};
#pragma unroll
        for (int dt = 0; dt < 16; ++dt) {
            short8 a  = *(const short8*)(abase + ((dt * 64 + g4 * 16) ^ asw));
            short8 f6 = *(const short8*)(p6 + (size_t)dt * DT_STRIDE);
            acc6 = __builtin_amdgcn_mfma_f32_16x16x32_bf16(a, f6, acc6, 0, 0, 0);
        }
        if (96 + r16 < Kq) {
            float adj6 = nAdj[96 + r16];
#pragma unroll
            for (int r = 0; r < 4; ++r)
                contrib += log_sigmoid(-(acc6[r] + adj6));
        }
        // ---- Target epilogue: lanes 0..15 own one position each ----
        if (g4 == 0) {
            int tg = target[pos0 + r16];
            float xt = tdot[r16] + emb_b[tg] - NORM_TERM - lpn[tg] - LOGK;
            contrib += log_sigmoid(xt);
        }
    }

#pragma unroll
    for (int off = 32; off >= 1; off >>= 1)
        contrib += __shfl_xor(contrib, off);
    if (lane == 0) partials[(size_t)blockIdx.x * 4 + w] = contrib;
}

// Deterministic per-batch reduction: 64 batches x 64 partials each.
__global__ void finalize(const float* __restrict__ partials,
                         float* __restrict__ out) {
    __shared__ float s4[64][5];        // padded
    int t = threadIdx.x;               // 0..255
    int b = t >> 2, q = t & 3;
    float s = 0.f;
#pragma unroll
    for (int i = 0; i < 16; ++i) s += partials[b * 64 + q * 16 + i];
    s4[b][q] = s;
    __syncthreads();
    if (t < 64) out[t] = s4[t][0] + s4[t][1] + s4[t][2] + s4[t][3];
}

extern "C" void kernel_launch(void* const* d_in, const int* in_sizes, int n_in,
                              void* d_out, int out_size, void* d_ws, size_t ws_size,
                              hipStream_t stream) {
    const float* input = (const float*)d_in[0];
    const float* emb_w = (const float*)d_in[1];
    const float* emb_b = (const float*)d_in[2];
    const float* lpn   = (const float*)d_in[3];
    const int*   tgt   = (const int*)d_in[4];
    const int*   ns    = (const int*)d_in[5];
    float* out = (float*)d_out;

    // ws layout: [0,114688) nBT bf16; [114688,115200) nAdj(+pad);
    // [115200,131584) partials[4096].
    unsigned short* nBT = (unsigned short*)d_ws;
    float* nAdj     = (float*)((char*)d_ws + (size_t)KP * Dq * 2);
    float* partials = (float*)((char*)d_ws + (size_t)KP * Dq * 2 + 512);

    prep_noise<<<KP, 128, 0, stream>>>(emb_w, emb_b, lpn, ns, nBT, nAdj);
    nce_main<<<NBLK, 256, 0, stream>>>(input, emb_w, emb_b, lpn, tgt, nBT, nAdj,
                                       partials);
    finalize<<<1, 256, 0, stream>>>(partials, out);
}

// Round 10
// 27.277 us; speedup vs baseline: 1.0614x; 1.0614x over previous
//
#include <hip/hip_runtime.h>
#include <math.h>

// Problem constants
#define Dq 512
#define Vq 50257
#define Kq 100
#define KP 112              // K padded to 7*16
#define NORM_TERM 10.8249051f   // log(50257)
#define LOGK 4.6051702f         // log(100)
#define NBLK 512            // 16384 positions / 32 per block
#define DT_STRIDE 3584      // KP*32 elements per d-chunk slab

typedef __attribute__((ext_vector_type(8))) short short8;
typedef __attribute__((ext_vector_type(4))) float floatx4;
typedef __attribute__((ext_vector_type(4))) unsigned short ushort4v;
typedef __attribute__((ext_vector_type(8))) unsigned short ushort8v;

__device__ __forceinline__ unsigned short f2bf(float f) {
    union { float f; unsigned u; } v; v.f = f;
    unsigned r = v.u + 0x7FFFu + ((v.u >> 16) & 1u);   // RNE
    return (unsigned short)(r >> 16);
}

__device__ __forceinline__ short8 cvt8(floatx4 a, floatx4 b) {
    short8 o;
    o[0] = (short)f2bf(a.x); o[1] = (short)f2bf(a.y);
    o[2] = (short)f2bf(a.z); o[3] = (short)f2bf(a.w);
    o[4] = (short)f2bf(b.x); o[5] = (short)f2bf(b.y);
    o[6] = (short)f2bf(b.z); o[7] = (short)f2bf(b.w);
    return o;
}

__device__ __forceinline__ float dot4(floatx4 a, floatx4 b) {
    return a.x*b.x + a.y*b.y + a.z*b.z + a.w*b.w;
}

__device__ __forceinline__ float log_sigmoid(float x) {
    return fminf(x, 0.f) - __logf(1.f + __expf(-fabsf(x)));
}

// Gather + convert noise rows to bf16, TRANSPOSED chunk-major layout:
// element (k, d) at nBT[(d>>5)*DT_STRIDE + k*32 + (d&31)]. A wave reading
// 16 k-rows x 4 chunks of one dt hits ONE contiguous 1KB block.
__global__ void prep_noise(const float* __restrict__ emb_w,
                           const float* __restrict__ emb_b,
                           const float* __restrict__ lpn,
                           const int* __restrict__ ns,
                           unsigned short* __restrict__ nBT,
                           float* __restrict__ nAdj) {
    int k = blockIdx.x;     // 0..111
    int t = threadIdx.x;    // 0..127; d = t*4 .. t*4+3
    size_t off = (size_t)(t >> 3) * DT_STRIDE + k * 32 + (t & 7) * 4;
    if (k < Kq) {
        int row = ns[k];
        floatx4 v = ((const floatx4*)(emb_w + (size_t)row * Dq))[t];
        ushort4v o;
        o.x = f2bf(v.x); o.y = f2bf(v.y); o.z = f2bf(v.z); o.w = f2bf(v.w);
        *(ushort4v*)(nBT + off) = o;
        if (t == 0) nAdj[k] = emb_b[row] - NORM_TERM - lpn[row] - LOGK;
    } else {
        ushort4v z; z.x = 0; z.y = 0; z.z = 0; z.w = 0;
        *(ushort4v*)(nBT + off) = z;
        if (t == 0) nAdj[k] = 0.f;
    }
}

// Block = 8 waves (512 thr) = 32 positions (two 16-row M-tiles).
// Staging: each wave stages 4 rows (full-row 2KB bursts for input+target,
// fp32 target dot shfl-reduced to tdot[], input row -> LDS bf16 swizzled).
// ONE barrier. Noise phase: wave w<7 owns k-tile w with TWO accumulators
// (M rows 0-15 and 16-31) -> each 1KB B-burst feeds 2 MFMAs (B reuse x2,
// noise L2 traffic halved vs 16-pos blocks). Wave 7: 32 target epilogues.
__global__ __launch_bounds__(512, 4) void nce_main(
    const float* __restrict__ input,     // [16384][512]
    const float* __restrict__ emb_w,     // [V][512]
    const float* __restrict__ emb_b,     // [V]
    const float* __restrict__ lpn,       // [V]
    const int* __restrict__ target,      // [16384]
    const unsigned short* __restrict__ nBT,  // [16][112][32] bf16
    const float* __restrict__ nAdj,          // [112]
    float* __restrict__ partials)            // [4096]
{
    __shared__ unsigned short A_lds[32 * 512];  // byte: row*1024 + (2c ^ ((row&7)<<4))
    __shared__ float tdot[32];

    int tid  = threadIdx.x;
    int lane = tid & 63;
    int w    = tid >> 6;            // 0..7
    int pos0 = (int)blockIdx.x * 32;
    int r16  = lane & 15;
    int g4   = lane >> 4;

    // ---- Stage: 4 rows per wave; full-row 2KB bursts for input & target ----
#pragma unroll
    for (int j = 0; j < 4; ++j) {
        int row = w * 4 + j;                         // 0..31
        const float* src = input + (size_t)(pos0 + row) * Dq + lane * 8;
        int tg = target[pos0 + row];                 // wave-uniform -> scalar
        const float* tsrc = emb_w + (size_t)tg * Dq + lane * 8;
        floatx4 x0 = *(const floatx4*)(src);
        floatx4 x1 = *(const floatx4*)(src + 4);
        floatx4 t0 = *(const floatx4*)(tsrc);
        floatx4 t1 = *(const floatx4*)(tsrc + 4);
        float s = dot4(x0, t0) + dot4(x1, t1);
#pragma unroll
        for (int off = 32; off >= 1; off >>= 1)
            s += __shfl_xor(s, off);
        if (lane == 0) tdot[row] = s;
        char* base = (char*)A_lds + row * 1024;
        *(ushort8v*)(base + ((lane * 16) ^ ((row & 7) << 4))) = (ushort8v)cvt8(x0, x1);
    }
    __syncthreads();

    float contrib = 0.f;

    if (w < 7) {
        // ---- Noise k-tile w vs BOTH M-tiles: 1 B-burst -> 2 MFMAs ----
        const char* a0base = (const char*)A_lds + r16 * 1024;          // rows 0-15
        const char* a1base = a0base + 16 * 1024;                       // rows 16-31
        int asw = (r16 & 7) << 4;   // same swizzle for row and row+16
        const unsigned short* p = nBT + (size_t)w * 512 + r16 * 32 + g4 * 8;
        floatx4 acc0 = {0.f, 0.f, 0.f, 0.f};
        floatx4 acc1 = {0.f, 0.f, 0.f, 0.f};
#pragma unroll
        for (int dt = 0; dt < 16; ++dt) {
            int aoff = (dt * 64 + g4 * 16) ^ asw;
            short8 a0 = *(const short8*)(a0base + aoff);
            short8 a1 = *(const short8*)(a1base + aoff);
            short8 f  = *(const short8*)(p + (size_t)dt * DT_STRIDE);
            acc0 = __builtin_amdgcn_mfma_f32_16x16x32_bf16(a0, f, acc0, 0, 0, 0);
            acc1 = __builtin_amdgcn_mfma_f32_16x16x32_bf16(a1, f, acc1, 0, 0, 0);
        }
        int k = w * 16 + r16;
        if (k < Kq) {
            float adj = nAdj[k];
#pragma unroll
            for (int r = 0; r < 4; ++r) {
                contrib += log_sigmoid(-(acc0[r] + adj));
                contrib += log_sigmoid(-(acc1[r] + adj));
            }
        }
    } else {
        // ---- Target epilogue: lanes 0..31 own one position each ----
        if (g4 < 2) {
            int p32 = g4 * 16 + r16;                 // 0..31
            int tg = target[pos0 + p32];
            float xt = tdot[p32] + emb_b[tg] - NORM_TERM - lpn[tg] - LOGK;
            contrib += log_sigmoid(xt);
        }
    }

#pragma unroll
    for (int off = 32; off >= 1; off >>= 1)
        contrib += __shfl_xor(contrib, off);
    if (lane == 0) partials[(size_t)blockIdx.x * 8 + w] = contrib;
}

// Deterministic per-batch reduction: 64 batches x 64 partials each.
__global__ void finalize(const float* __restrict__ partials,
                         float* __restrict__ out) {
    __shared__ float s4[64][5];        // padded
    int t = threadIdx.x;               // 0..255
    int b = t >> 2, q = t & 3;
    float s = 0.f;
#pragma unroll
    for (int i = 0; i < 16; ++i) s += partials[b * 64 + q * 16 + i];
    s4[b][q] = s;
    __syncthreads();
    if (t < 64) out[t] = s4[t][0] + s4[t][1] + s4[t][2] + s4[t][3];
}

extern "C" void kernel_launch(void* const* d_in, const int* in_sizes, int n_in,
                              void* d_out, int out_size, void* d_ws, size_t ws_size,
                              hipStream_t stream) {
    const float* input = (const float*)d_in[0];
    const float* emb_w = (const float*)d_in[1];
    const float* emb_b = (const float*)d_in[2];
    const float* lpn   = (const float*)d_in[3];
    const int*   tgt   = (const int*)d_in[4];
    const int*   ns    = (const int*)d_in[5];
    float* out = (float*)d_out;

    // ws layout: [0,114688) nBT bf16; [114688,115200) nAdj(+pad);
    // [115200,131584) partials[4096].
    unsigned short* nBT = (unsigned short*)d_ws;
    float* nAdj     = (float*)((char*)d_ws + (size_t)KP * Dq * 2);
    float* partials = (float*)((char*)d_ws + (size_t)KP * Dq * 2 + 512);

    prep_noise<<<KP, 128, 0, stream>>>(emb_w, emb_b, lpn, ns, nBT, nAdj);
    nce_main<<<NBLK, 512, 0, stream>>>(input, emb_w, emb_b, lpn, tgt, nBT, nAdj,
                                       partials);
    finalize<<<1, 256, 0, stream>>>(partials, out);
}

// Round 11
// 27.220 us; speedup vs baseline: 1.0636x; 1.0021x over previous
//
#include <hip/hip_runtime.h>
#include <math.h>

// Problem constants
#define Dq 512
#define Vq 50257
#define Kq 100
#define KP 112              // K padded to 7*16
#define NORM_TERM 10.8249051f   // log(50257)
#define LOGK 4.6051702f         // log(100)
#define NBLK 512            // 16384 positions / 32 per block
#define DT_STRIDE 3584      // KP*32 elements per d-chunk slab

typedef __attribute__((ext_vector_type(8))) short short8;
typedef __attribute__((ext_vector_type(4))) float floatx4;
typedef __attribute__((ext_vector_type(4))) unsigned short ushort4v;
typedef __attribute__((ext_vector_type(8))) unsigned short ushort8v;

__device__ __forceinline__ unsigned short f2bf(float f) {
    union { float f; unsigned u; } v; v.f = f;
    unsigned r = v.u + 0x7FFFu + ((v.u >> 16) & 1u);   // RNE
    return (unsigned short)(r >> 16);
}

__device__ __forceinline__ short8 cvt8(floatx4 a, floatx4 b) {
    short8 o;
    o[0] = (short)f2bf(a.x); o[1] = (short)f2bf(a.y);
    o[2] = (short)f2bf(a.z); o[3] = (short)f2bf(a.w);
    o[4] = (short)f2bf(b.x); o[5] = (short)f2bf(b.y);
    o[6] = (short)f2bf(b.z); o[7] = (short)f2bf(b.w);
    return o;
}

__device__ __forceinline__ float dot4(floatx4 a, floatx4 b) {
    return a.x*b.x + a.y*b.y + a.z*b.z + a.w*b.w;
}

__device__ __forceinline__ float log_sigmoid(float x) {
    return fminf(x, 0.f) - __logf(1.f + __expf(-fabsf(x)));
}

// Gather + convert noise rows to bf16, TRANSPOSED chunk-major layout:
// element (k, d) at nBT[(d>>5)*DT_STRIDE + k*32 + (d&31)]. A wave reading
// 16 k-rows x 4 chunks of one dt hits ONE contiguous 1KB block.
__global__ void prep_noise(const float* __restrict__ emb_w,
                           const float* __restrict__ emb_b,
                           const float* __restrict__ lpn,
                           const int* __restrict__ ns,
                           unsigned short* __restrict__ nBT,
                           float* __restrict__ nAdj) {
    int k = blockIdx.x;     // 0..111
    int t = threadIdx.x;    // 0..127; d = t*4 .. t*4+3
    size_t off = (size_t)(t >> 3) * DT_STRIDE + k * 32 + (t & 7) * 4;
    if (k < Kq) {
        int row = ns[k];
        floatx4 v = ((const floatx4*)(emb_w + (size_t)row * Dq))[t];
        ushort4v o;
        o.x = f2bf(v.x); o.y = f2bf(v.y); o.z = f2bf(v.z); o.w = f2bf(v.w);
        *(ushort4v*)(nBT + off) = o;
        if (t == 0) nAdj[k] = emb_b[row] - NORM_TERM - lpn[row] - LOGK;
    } else {
        ushort4v z; z.x = 0; z.y = 0; z.z = 0; z.w = 0;
        *(ushort4v*)(nBT + off) = z;
        if (t == 0) nAdj[k] = 0.f;
    }
}

// Block = 8 waves (512 thr) = 32 positions (two 16-row M-tiles).
// PHASE-OVERLAP: wave w<7 issues ALL 16 noise B-frag loads at entry; their
// latency hides under the staging phase (the vmcnt(0) drain at the barrier
// guarantees arrival). Staging: each wave stages 4 rows (full-row 2KB
// bursts input+target, fp32 target dot shfl-reduced to tdot[], input ->
// LDS bf16 swizzled). After the ONE barrier the compute loop is pure
// {2 ds_read + 2 MFMA} - zero global loads. Wave 7: 32 target epilogues.
__global__ __launch_bounds__(512, 4) void nce_main(
    const float* __restrict__ input,     // [16384][512]
    const float* __restrict__ emb_w,     // [V][512]
    const float* __restrict__ emb_b,     // [V]
    const float* __restrict__ lpn,       // [V]
    const int* __restrict__ target,      // [16384]
    const unsigned short* __restrict__ nBT,  // [16][112][32] bf16
    const float* __restrict__ nAdj,          // [112]
    float* __restrict__ partials)            // [4096]
{
    __shared__ unsigned short A_lds[32 * 512];  // byte: row*1024 + (2c ^ ((row&7)<<4))
    __shared__ float tdot[32];

    int tid  = threadIdx.x;
    int lane = tid & 63;
    int w    = tid >> 6;            // 0..7
    int pos0 = (int)blockIdx.x * 32;
    int r16  = lane & 15;
    int g4   = lane >> 4;

    // ---- Prefetch: issue all 16 B-frag loads NOW (consumed post-barrier) ----
    short8 bf[16];
    if (w < 7) {
        const unsigned short* p = nBT + (size_t)w * 512 + r16 * 32 + g4 * 8;
#pragma unroll
        for (int dt = 0; dt < 16; ++dt)
            bf[dt] = *(const short8*)(p + (size_t)dt * DT_STRIDE);
    }

    // ---- Stage: 4 rows per wave; full-row 2KB bursts for input & target ----
#pragma unroll
    for (int j = 0; j < 4; ++j) {
        int row = w * 4 + j;                         // 0..31
        const float* src = input + (size_t)(pos0 + row) * Dq + lane * 8;
        int tg = target[pos0 + row];                 // wave-uniform -> scalar
        const float* tsrc = emb_w + (size_t)tg * Dq + lane * 8;
        floatx4 x0 = *(const floatx4*)(src);
        floatx4 x1 = *(const floatx4*)(src + 4);
        floatx4 t0 = *(const floatx4*)(tsrc);
        floatx4 t1 = *(const floatx4*)(tsrc + 4);
        float s = dot4(x0, t0) + dot4(x1, t1);
#pragma unroll
        for (int off = 32; off >= 1; off >>= 1)
            s += __shfl_xor(s, off);
        if (lane == 0) tdot[row] = s;
        char* base = (char*)A_lds + row * 1024;
        *(ushort8v*)(base + ((lane * 16) ^ ((row & 7) << 4))) = (ushort8v)cvt8(x0, x1);
    }
    __syncthreads();

    float contrib = 0.f;

    if (w < 7) {
        // ---- Noise k-tile w vs BOTH M-tiles: pure LDS + MFMA ----
        const char* a0base = (const char*)A_lds + r16 * 1024;          // rows 0-15
        const char* a1base = a0base + 16 * 1024;                       // rows 16-31
        int asw = (r16 & 7) << 4;   // same swizzle for row and row+16
        floatx4 acc0 = {0.f, 0.f, 0.f, 0.f};
        floatx4 acc1 = {0.f, 0.f, 0.f, 0.f};
#pragma unroll
        for (int dt = 0; dt < 16; ++dt) {
            int aoff = (dt * 64 + g4 * 16) ^ asw;
            short8 a0 = *(const short8*)(a0base + aoff);
            short8 a1 = *(const short8*)(a1base + aoff);
            acc0 = __builtin_amdgcn_mfma_f32_16x16x32_bf16(a0, bf[dt], acc0, 0, 0, 0);
            acc1 = __builtin_amdgcn_mfma_f32_16x16x32_bf16(a1, bf[dt], acc1, 0, 0, 0);
        }
        int k = w * 16 + r16;
        if (k < Kq) {
            float adj = nAdj[k];
#pragma unroll
            for (int r = 0; r < 4; ++r) {
                contrib += log_sigmoid(-(acc0[r] + adj));
                contrib += log_sigmoid(-(acc1[r] + adj));
            }
        }
    } else {
        // ---- Target epilogue: lanes 0..31 own one position each ----
        if (g4 < 2) {
            int p32 = g4 * 16 + r16;                 // 0..31
            int tg = target[pos0 + p32];
            float xt = tdot[p32] + emb_b[tg] - NORM_TERM - lpn[tg] - LOGK;
            contrib += log_sigmoid(xt);
        }
    }

#pragma unroll
    for (int off = 32; off >= 1; off >>= 1)
        contrib += __shfl_xor(contrib, off);
    if (lane == 0) partials[(size_t)blockIdx.x * 8 + w] = contrib;
}

// Deterministic per-batch reduction: 64 batches x 64 partials each.
__global__ void finalize(const float* __restrict__ partials,
                         float* __restrict__ out) {
    __shared__ float s4[64][5];        // padded
    int t = threadIdx.x;               // 0..255
    int b = t >> 2, q = t & 3;
    float s = 0.f;
#pragma unroll
    for (int i = 0; i < 16; ++i) s += partials[b * 64 + q * 16 + i];
    s4[b][q] = s;
    __syncthreads();
    if (t < 64) out[t] = s4[t][0] + s4[t][1] + s4[t][2] + s4[t][3];
}

extern "C" void kernel_launch(void* const* d_in, const int* in_sizes, int n_in,
                              void* d_out, int out_size, void* d_ws, size_t ws_size,
                              hipStream_t stream) {
    const float* input = (const float*)d_in[0];
    const float* emb_w = (const float*)d_in[1];
    const float* emb_b = (const float*)d_in[2];
    const float* lpn   = (const float*)d_in[3];
    const int*   tgt   = (const int*)d_in[4];
    const int*   ns    = (const int*)d_in[5];
    float* out = (float*)d_out;

    // ws layout: [0,114688) nBT bf16; [114688,115200) nAdj(+pad);
    // [115200,131584) partials[4096].
    unsigned short* nBT = (unsigned short*)d_ws;
    float* nAdj     = (float*)((char*)d_ws + (size_t)KP * Dq * 2);
    float* partials = (float*)((char*)d_ws + (size_t)KP * Dq * 2 + 512);

    prep_noise<<<KP, 128, 0, stream>>>(emb_w, emb_b, lpn, ns, nBT, nAdj);
    nce_main<<<NBLK, 512, 0, stream>>>(input, emb_w, emb_b, lpn, tgt, nBT, nAdj,
                                       partials);
    finalize<<<1, 256, 0, stream>>>(partials, out);
}